// Round 3
// baseline (643.618 us; speedup 1.0000x reference)
//
#include <hip/hip_runtime.h>
#include <stdint.h>

// Problem constants (B=32, D=256, H=32, W=32, K=2048)
#define K_CODES 2048
#define DIM 256
#define NROWS 32768            // B*H*W
#define ROWS_PER_BLOCK 16
#define THREADS 512            // 8 waves
#define HW_STRIDE 1024         // H*W
#define QLOSS_OFFSET 8388608
#define PROB_OFFSET 8388609ULL
#define ZB_PITCH 264           // ushorts per LDS z-row: 256 + 8 pad
#define NBLOCKS (NROWS / ROWS_PER_BLOCK)   // 2048
#define CPX (NBLOCKS / 8)                  // 256 blocks per XCD chunk

typedef short v8s __attribute__((ext_vector_type(8)));   // 8 bf16 (MFMA operand)
typedef float v4f __attribute__((ext_vector_type(4)));
typedef __fp16 v2h __attribute__((ext_vector_type(2))); // matches cvt_pkrtz return type

__device__ __forceinline__ ushort f2bf(float x) {
    uint32_t u = __float_as_uint(x);
    return (ushort)((u + 0x7FFFu + ((u >> 16) & 1u)) >> 16);   // RNE
}

// Prep: codebook fp32 -> bf16 (ws), cnorm[k] = sum c^2, zero the q_loss slot.
__global__ void prep_kernel(const float* __restrict__ cb, ushort* __restrict__ cbb,
                            float* __restrict__ cnorm, float* __restrict__ qloss) {
    const int code = blockIdx.x;
    const int lane = threadIdx.x;     // 64 threads
    float4 v = ((const float4*)(cb + code * DIM))[lane];
    ushort4 o;
    o.x = f2bf(v.x); o.y = f2bf(v.y); o.z = f2bf(v.z); o.w = f2bf(v.w);
    ((ushort4*)(cbb + code * DIM))[lane] = o;
    float ss = v.x * v.x + v.y * v.y + v.z * v.z + v.w * v.w;
    #pragma unroll
    for (int m = 32; m >= 1; m >>= 1) ss += __shfl_xor(ss, m, 64);
    if (lane == 0) cnorm[code] = ss;
    if (code == 0 && lane == 0) *qloss = 0.f;
}

// cap at 128 arch VGPR (4 waves/EU) so two 8-wave blocks co-reside per CU
__launch_bounds__(THREADS, 4)
__global__ void vq_kernel(const float* __restrict__ z, const float* __restrict__ cb,
                          const ushort* __restrict__ cbb, const float* __restrict__ cnorm,
                          float* __restrict__ out) {
    __shared__ float zf[DIM * 16];                       // [d][m] fp32, 16 KB
    __shared__ ushort zb[ROWS_PER_BLOCK * ZB_PITCH];     // [m][k] bf16, padded
    __shared__ float red_sum[8][16];
    __shared__ float red_val[8][16];
    __shared__ int   red_code[8][16];
    __shared__ float row_sum[16];
    __shared__ int   row_idx[16];
    __shared__ float lred[8];

    const int t = threadIdx.x;
    // XCD-chunk swizzle (bijective: 2048 % 8 == 0): consecutive logical blocks
    // share 128B z-lines -> keep them on one XCD's L2.
    const int bid = ((int)blockIdx.x & 7) * CPX + ((int)blockIdx.x >> 3);
    const int n0 = bid * ROWS_PER_BLOCK;                 // first global row
    const int bb = n0 >> 10;                             // batch index
    const int hw = n0 & 1023;                            // h*32 + w0 (16-aligned)
    const float* zbase = z + (size_t)bb * (DIM * HW_STRIDE) + hw;

    // ---- stage z -> zf [d][m] (coalesced float4: 4 consecutive w per d) ----
    #pragma unroll
    for (int j = 0; j < 2; ++j) {
        int i4 = t + j * THREADS;                        // 0..1023
        int d = i4 >> 2, m0 = (i4 & 3) << 2;
        float4 v = *(const float4*)(zbase + (size_t)d * HW_STRIDE + m0);
        *(float4*)&zf[d * 16 + m0] = v;
    }
    __syncthreads();
    // ---- transpose zf -> zb bf16 [m][k] for MFMA A-fragments ----
    #pragma unroll
    for (int j = 0; j < 4; ++j) {
        int i2 = t + j * THREADS;                        // 0..2047
        int m = i2 & 15, kp = i2 >> 4;                   // kp = k/2, 0..127
        float a0 = zf[(2 * kp) * 16 + m];
        float a1 = zf[(2 * kp + 1) * 16 + m];
        uint32_t pk = (uint32_t)f2bf(a0) | ((uint32_t)f2bf(a1) << 16);
        *(uint32_t*)&zb[m * ZB_PITCH + 2 * kp] = pk;
    }
    __syncthreads();

    const int wave = t >> 6, lane = t & 63;
    const int q = lane >> 4, lm = lane & 15;
    const int c0 = wave * 256;                           // this wave's code range

    // A fragments: lane holds A[m=lm][k = ks*32 + q*8 + j], all 8 k-steps (32 regs)
    v8s afrag[8];
    const ushort* arow = &zb[lm * ZB_PITCH + q * 8];
    #pragma unroll
    for (int ks = 0; ks < 8; ++ks) afrag[ks] = *(const v8s*)(arow + ks * 32);

    // prefetch cnorm for this lane's 16 codes (kills the per-ct dependent load)
    float cnr[16];
    #pragma unroll
    for (int ct = 0; ct < 16; ++ct) cnr[ct] = cnorm[c0 + ct * 16 + lm];

    // K-loop: 16 col-tiles x 8 k-steps, software-pipelined one tile deep:
    // B fragments for ct+1 are issued before ct's MFMA chain, so L2 latency
    // hides under ~300cy of MFMA+exp work per wave (x4 waves/SIMD).
    const ushort* bptr = cbb + (size_t)(c0 + lm) * DIM + q * 8;  // code = c0+ct*16+lm
    v8s bb0[8];
    #pragma unroll
    for (int ks = 0; ks < 8; ++ks) bb0[ks] = *(const v8s*)(bptr + ks * 32);

    v2h ep[32];
    float sume[4] = {0.f, 0.f, 0.f, 0.f};
    float bval[4] = {-1e30f, -1e30f, -1e30f, -1e30f};
    int   bcode[4] = {0, 0, 0, 0};
    #pragma unroll
    for (int ct = 0; ct < 16; ++ct) {
        v8s bb1[8];
        if (ct < 15) {
            const ushort* np = bptr + (size_t)(ct + 1) * (16 * DIM);
            #pragma unroll
            for (int ks = 0; ks < 8; ++ks) bb1[ks] = *(const v8s*)(np + ks * 32);
        }
        v4f a = {0.f, 0.f, 0.f, 0.f};
        #pragma unroll
        for (int ks = 0; ks < 8; ++ks)
            a = __builtin_amdgcn_mfma_f32_16x16x32_bf16(afrag[ks], bb0[ks], a, 0, 0, 0);
        const float cn = cnr[ct];
        const int code = c0 + ct * 16 + lm;
        #pragma unroll
        for (int r = 0; r < 4; ++r) {
            float l = 2.f * a[r] - cn;                   // logit = 2 z.c - |c|^2 (|z|^2 cancels)
            float ev = __expf(l);
            sume[r] += ev;
            if (l > bval[r]) { bval[r] = l; bcode[r] = code; }
            a[r] = ev;
        }
        ep[2 * ct]     = __builtin_amdgcn_cvt_pkrtz(a[0], a[1]);
        ep[2 * ct + 1] = __builtin_amdgcn_cvt_pkrtz(a[2], a[3]);
        #pragma unroll
        for (int ks = 0; ks < 8; ++ks) bb0[ks] = bb1[ks];  // renamed away (full unroll)
    }
    // butterfly across the 16 lanes (lm) of each quad-row group
    #pragma unroll
    for (int m = 1; m <= 8; m <<= 1) {
        #pragma unroll
        for (int r = 0; r < 4; ++r) {
            sume[r] += __shfl_xor(sume[r], m, 64);
            float v2 = __shfl_xor(bval[r], m, 64);
            int   c2 = __shfl_xor(bcode[r], m, 64);
            if (v2 > bval[r] || (v2 == bval[r] && c2 < bcode[r])) { bval[r] = v2; bcode[r] = c2; }
        }
    }
    if (lm == 0) {
        #pragma unroll
        for (int r = 0; r < 4; ++r) {
            red_sum[wave][q * 4 + r]  = sume[r];
            red_val[wave][q * 4 + r]  = bval[r];
            red_code[wave][q * 4 + r] = bcode[r];
        }
    }
    __syncthreads();
    if (t < 16) {
        float s = 0.f, bv = -1e30f;
        int bc = 0;
        #pragma unroll
        for (int w = 0; w < 8; ++w) {
            s += red_sum[w][t];
            float v = red_val[w][t];
            int   c = red_code[w][t];
            if (v > bv || (v == bv && c < bc)) { bv = v; bc = c; }
        }
        row_sum[t] = s;
        row_idx[t] = bc;
    }
    __syncthreads();

    // ---- distance_prob writes (nontemporal: keep codebook L2-resident) ----
    float rinv[4];
    #pragma unroll
    for (int r = 0; r < 4; ++r) rinv[r] = 1.f / row_sum[q * 4 + r];
    float* prob = out + PROB_OFFSET;
    #pragma unroll
    for (int ct = 0; ct < 16; ++ct) {
        int col = c0 + ct * 16 + lm;
        float e0 = (float)ep[2 * ct][0];
        float e1 = (float)ep[2 * ct][1];
        float e2 = (float)ep[2 * ct + 1][0];
        float e3 = (float)ep[2 * ct + 1][1];
        size_t base = (size_t)(n0 + q * 4) * K_CODES + col;
        __builtin_nontemporal_store(e0 * rinv[0], prob + base);
        __builtin_nontemporal_store(e1 * rinv[1], prob + base + K_CODES);
        __builtin_nontemporal_store(e2 * rinv[2], prob + base + 2 * K_CODES);
        __builtin_nontemporal_store(e3 * rinv[3], prob + base + 3 * K_CODES);
    }

    // ---- z_q output (gather codebook rows, scatter back to (b,d,h,w)) + q_loss ----
    float lacc = 0.f;
    #pragma unroll
    for (int j = 0; j < 2; ++j) {
        int i4 = t + j * THREADS;
        int d = i4 >> 2, m0 = (i4 & 3) << 2;
        float ov[4];
        #pragma unroll
        for (int i = 0; i < 4; ++i) {
            int m = m0 + i;
            float cv = cb[row_idx[m] * DIM + d];
            float zv = zf[d * 16 + m];
            float df = zv - cv;
            lacc += df * df;
            ov[i] = cv;
        }
        v4f o4 = {ov[0], ov[1], ov[2], ov[3]};           // clang vector: builtin-compatible
        __builtin_nontemporal_store(
            o4, (v4f*)(out + (size_t)bb * (DIM * HW_STRIDE) + hw + (size_t)d * HW_STRIDE + m0));
    }
    #pragma unroll
    for (int m = 32; m >= 1; m >>= 1) lacc += __shfl_xor(lacc, m, 64);
    if (lane == 0) lred[wave] = lacc;
    __syncthreads();
    if (t == 0) {
        float s = 0.f;
        #pragma unroll
        for (int w = 0; w < 8; ++w) s += lred[w];
        // q_loss = (1 + BETA) * mean((z_q - z)^2); both loss terms coincide in fwd
        atomicAdd(out + QLOSS_OFFSET, s * (1.25f / 8388608.f));
    }
}

extern "C" void kernel_launch(void* const* d_in, const int* in_sizes, int n_in,
                              void* d_out, int out_size, void* d_ws, size_t ws_size,
                              hipStream_t stream) {
    const float* z  = (const float*)d_in[0];   // (32,256,32,32) fp32
    const float* cb = (const float*)d_in[1];   // (2048,256) fp32
    float* out = (float*)d_out;
    ushort* cbb  = (ushort*)d_ws;                                  // bf16 codebook, 1 MB
    float*  cnm  = (float*)((char*)d_ws + (size_t)K_CODES * DIM * sizeof(ushort));
    prep_kernel<<<K_CODES, 64, 0, stream>>>(cb, cbb, cnm, out + QLOSS_OFFSET);
    vq_kernel<<<NBLOCKS, THREADS, 0, stream>>>(z, cb, cbb, cnm, out);
}

// Round 4
// 571.898 us; speedup vs baseline: 1.1254x; 1.1254x over previous
//
#include <hip/hip_runtime.h>
#include <stdint.h>

// Problem constants (B=32, D=256, H=32, W=32, K=2048)
#define K_CODES 2048
#define DIM 256
#define NROWS 32768            // B*H*W
#define ROWS_PER_BLOCK 16
#define THREADS 512            // 8 waves
#define HW_STRIDE 1024         // H*W
#define QLOSS_OFFSET 8388608
#define PROB_OFFSET 8388609ULL
#define ZB_PITCH 264           // ushorts per LDS z-row: 256 + 8 pad
#define EP_PITCH 2052          // fp16 per prob row: 2048 + 4 pad (bank spread)
#define NBLOCKS (NROWS / ROWS_PER_BLOCK)   // 2048
#define CPX (NBLOCKS / 8)                  // 256 blocks per XCD chunk

typedef short v8s __attribute__((ext_vector_type(8)));   // 8 bf16 (MFMA operand)
typedef float v4f __attribute__((ext_vector_type(4)));
typedef __fp16 v4h __attribute__((ext_vector_type(4)));

__device__ __forceinline__ ushort f2bf(float x) {
    uint32_t u = __float_as_uint(x);
    return (ushort)((u + 0x7FFFu + ((u >> 16) & 1u)) >> 16);   // RNE
}

// Prep: codebook fp32 -> bf16 (ws), cnorm[k] = sum c^2, zero the q_loss slot.
__global__ void prep_kernel(const float* __restrict__ cb, ushort* __restrict__ cbb,
                            float* __restrict__ cnorm, float* __restrict__ qloss) {
    const int code = blockIdx.x;
    const int lane = threadIdx.x;     // 64 threads
    float4 v = ((const float4*)(cb + code * DIM))[lane];
    ushort4 o;
    o.x = f2bf(v.x); o.y = f2bf(v.y); o.z = f2bf(v.z); o.w = f2bf(v.w);
    ((ushort4*)(cbb + code * DIM))[lane] = o;
    float ss = v.x * v.x + v.y * v.y + v.z * v.z + v.w * v.w;
    #pragma unroll
    for (int m = 32; m >= 1; m >>= 1) ss += __shfl_xor(ss, m, 64);
    if (lane == 0) cnorm[code] = ss;
    if (code == 0 && lane == 0) *qloss = 0.f;
}

// 4 waves/EU -> 128-reg total budget; two 8-wave blocks co-reside per CU
// (LDS 75.8 KB/block is the binding 2-block limit).
__launch_bounds__(THREADS, 4)
__global__ void vq_kernel(const float* __restrict__ z, const float* __restrict__ cb,
                          const ushort* __restrict__ cbb, const float* __restrict__ cnorm,
                          float* __restrict__ out) {
    // eplds: fp16 exp matrix [16 rows][2052] = 64.1 KB. Its first 16 KB doubles
    // as the fp32 z staging area (zf) before the ct-loop starts writing exps.
    __shared__ __align__(16) ushort eplds[ROWS_PER_BLOCK * EP_PITCH];
    __shared__ ushort zb[ROWS_PER_BLOCK * ZB_PITCH];     // [m][k] bf16, padded
    __shared__ float red_sum[8][16];
    __shared__ float red_val[8][16];
    __shared__ int   red_code[8][16];
    __shared__ float row_sum[16];
    __shared__ int   row_idx[16];
    __shared__ float lred[8];

    const int t = threadIdx.x;
    // XCD-chunk swizzle (bijective: 2048 % 8 == 0): consecutive logical blocks
    // share 128B z/z_q lines -> keep them on one XCD's L2.
    const int bid = ((int)blockIdx.x & 7) * CPX + ((int)blockIdx.x >> 3);
    const int n0 = bid * ROWS_PER_BLOCK;                 // first global row
    const int bb = n0 >> 10;                             // batch index
    const int hw = n0 & 1023;                            // h*32 + w0 (16-aligned)
    const float* zbase = z + (size_t)bb * (DIM * HW_STRIDE) + hw;

    float* zf = (float*)eplds;                           // alias (pre-loop only)

    // ---- stage z -> zf [d][m]; keep own elements in zrf for the tail ----
    float zrf[8];
    #pragma unroll
    for (int j = 0; j < 2; ++j) {
        int i4 = t + j * THREADS;                        // 0..1023
        int d = i4 >> 2, m0 = (i4 & 3) << 2;
        float4 v = *(const float4*)(zbase + (size_t)d * HW_STRIDE + m0);
        zrf[4 * j + 0] = v.x; zrf[4 * j + 1] = v.y;
        zrf[4 * j + 2] = v.z; zrf[4 * j + 3] = v.w;
        *(float4*)&zf[d * 16 + m0] = v;
    }
    __syncthreads();
    // ---- transpose zf -> zb bf16 [m][k] for MFMA A-fragments ----
    #pragma unroll
    for (int j = 0; j < 4; ++j) {
        int i2 = t + j * THREADS;                        // 0..2047
        int m = i2 & 15, kp = i2 >> 4;                   // kp = k/2, 0..127
        float a0 = zf[(2 * kp) * 16 + m];
        float a1 = zf[(2 * kp + 1) * 16 + m];
        uint32_t pk = (uint32_t)f2bf(a0) | ((uint32_t)f2bf(a1) << 16);
        *(uint32_t*)&zb[m * ZB_PITCH + 2 * kp] = pk;
    }
    __syncthreads();
    // zf region dead from here; ct-loop writes exps into eplds.

    const int wave = t >> 6, lane = t & 63;
    const int q = lane >> 4, lm = lane & 15;
    const int c0 = wave * 256;                           // this wave's code range

    // A fragments: lane holds A[m=lm][k = ks*32 + q*8 + j], all 8 k-steps
    v8s afrag[8];
    const ushort* arow = &zb[lm * ZB_PITCH + q * 8];
    #pragma unroll
    for (int ks = 0; ks < 8; ++ks) afrag[ks] = *(const v8s*)(arow + ks * 32);

    // K-loop: 16 col-tiles x 8 k-steps, software-pipelined one tile deep.
    // With ep[] moved to LDS the live set fits the 128-reg budget, so bb1
    // prefetch can survive: loads for ct+1 hide L2 latency under ct's MFMA+exp.
    const ushort* bptr = cbb + (size_t)(c0 + lm) * DIM + q * 8;  // code = c0+ct*16+lm
    v8s bb0[8];
    #pragma unroll
    for (int ks = 0; ks < 8; ++ks) bb0[ks] = *(const v8s*)(bptr + ks * 32);
    float cn0 = cnorm[c0 + lm];

    __fp16* epf = (__fp16*)eplds;
    float sume[4] = {0.f, 0.f, 0.f, 0.f};
    float bval[4] = {-1e30f, -1e30f, -1e30f, -1e30f};
    int   bcode[4] = {0, 0, 0, 0};
    #pragma unroll
    for (int ct = 0; ct < 16; ++ct) {
        v8s bb1[8];
        float cn1;
        if (ct < 15) {
            const ushort* np = bptr + (size_t)(ct + 1) * (16 * DIM);
            #pragma unroll
            for (int ks = 0; ks < 8; ++ks) bb1[ks] = *(const v8s*)(np + ks * 32);
            cn1 = cnorm[c0 + (ct + 1) * 16 + lm];
        }
        v4f a = {0.f, 0.f, 0.f, 0.f};
        #pragma unroll
        for (int ks = 0; ks < 8; ++ks)
            a = __builtin_amdgcn_mfma_f32_16x16x32_bf16(afrag[ks], bb0[ks], a, 0, 0, 0);
        const int code = c0 + ct * 16 + lm;
        #pragma unroll
        for (int r = 0; r < 4; ++r) {
            float l = 2.f * a[r] - cn0;                  // logit = 2 z.c - |c|^2 (|z|^2 cancels)
            float ev = __expf(l);
            sume[r] += ev;
            if (l > bval[r]) { bval[r] = l; bcode[r] = code; }
            // [row = q*4+r][col = code]; banks: 2 lanes/dword -> conflict-free
            epf[(q * 4 + r) * EP_PITCH + code] = (__fp16)ev;
        }
        cn0 = cn1;
        #pragma unroll
        for (int ks = 0; ks < 8; ++ks) bb0[ks] = bb1[ks];  // renamed away (full unroll)
    }
    // butterfly across the 16 lanes (lm) of each quad-row group
    #pragma unroll
    for (int m = 1; m <= 8; m <<= 1) {
        #pragma unroll
        for (int r = 0; r < 4; ++r) {
            sume[r] += __shfl_xor(sume[r], m, 64);
            float v2 = __shfl_xor(bval[r], m, 64);
            int   c2 = __shfl_xor(bcode[r], m, 64);
            if (v2 > bval[r] || (v2 == bval[r] && c2 < bcode[r])) { bval[r] = v2; bcode[r] = c2; }
        }
    }
    if (lm == 0) {
        #pragma unroll
        for (int r = 0; r < 4; ++r) {
            red_sum[wave][q * 4 + r]  = sume[r];
            red_val[wave][q * 4 + r]  = bval[r];
            red_code[wave][q * 4 + r] = bcode[r];
        }
    }
    __syncthreads();
    if (t < 16) {
        float s = 0.f, bv = -1e30f;
        int bc = 0;
        #pragma unroll
        for (int w = 0; w < 8; ++w) {
            s += red_sum[w][t];
            float v = red_val[w][t];
            int   c = red_code[w][t];
            if (v > bv || (v == bv && c < bc)) { bv = v; bc = c; }
        }
        row_sum[t] = s;
        row_idx[t] = bc;
    }
    __syncthreads();

    // ---- z_q gather: issue codebook loads early (L2-hot, <=16 distinct rows);
    //      they complete while the prob store stream below is in flight ----
    float cv[8];
    #pragma unroll
    for (int j = 0; j < 2; ++j) {
        int i4 = t + j * THREADS;
        int d = i4 >> 2, m0 = (i4 & 3) << 2;
        #pragma unroll
        for (int i = 0; i < 4; ++i) cv[4 * j + i] = cb[row_idx[m0 + i] * DIM + d];
    }

    // ---- distance_prob: LDS-transposed coalesced stream.
    //      Per row: ds_read_b64 (4 fp16) -> scale -> one full-line dwordx4 store
    //      (wave writes 1 KB contiguous; 16 store insts/thread total). ----
    float* prob = out + PROB_OFFSET;
    #pragma unroll
    for (int rr = 0; rr < ROWS_PER_BLOCK; ++rr) {
        float rs = 1.f / row_sum[rr];                    // wave-uniform broadcast
        v4h e = *(const v4h*)&epf[rr * EP_PITCH + t * 4];
        v4f o = { e[0] * rs, e[1] * rs, e[2] * rs, e[3] * rs };
        *(v4f*)(prob + (size_t)(n0 + rr) * K_CODES + t * 4) = o;
    }

    // ---- z_q store (normal stores: L2 merges the 64B half-line chunks) + q_loss ----
    float lacc = 0.f;
    #pragma unroll
    for (int j = 0; j < 2; ++j) {
        int i4 = t + j * THREADS;
        int d = i4 >> 2, m0 = (i4 & 3) << 2;
        float ov[4];
        #pragma unroll
        for (int i = 0; i < 4; ++i) {
            float cvv = cv[4 * j + i];
            float df = zrf[4 * j + i] - cvv;
            lacc += df * df;
            ov[i] = cvv;
        }
        v4f o4 = {ov[0], ov[1], ov[2], ov[3]};
        *(v4f*)(out + (size_t)bb * (DIM * HW_STRIDE) + hw + (size_t)d * HW_STRIDE + m0) = o4;
    }
    #pragma unroll
    for (int m = 32; m >= 1; m >>= 1) lacc += __shfl_xor(lacc, m, 64);
    if (lane == 0) lred[wave] = lacc;
    __syncthreads();
    if (t == 0) {
        float s = 0.f;
        #pragma unroll
        for (int w = 0; w < 8; ++w) s += lred[w];
        // q_loss = (1 + BETA) * mean((z_q - z)^2); both loss terms coincide in fwd
        atomicAdd(out + QLOSS_OFFSET, s * (1.25f / 8388608.f));
    }
}

extern "C" void kernel_launch(void* const* d_in, const int* in_sizes, int n_in,
                              void* d_out, int out_size, void* d_ws, size_t ws_size,
                              hipStream_t stream) {
    const float* z  = (const float*)d_in[0];   // (32,256,32,32) fp32
    const float* cb = (const float*)d_in[1];   // (2048,256) fp32
    float* out = (float*)d_out;
    ushort* cbb  = (ushort*)d_ws;                                  // bf16 codebook, 1 MB
    float*  cnm  = (float*)((char*)d_ws + (size_t)K_CODES * DIM * sizeof(ushort));
    prep_kernel<<<K_CODES, 64, 0, stream>>>(cb, cbb, cnm, out + QLOSS_OFFSET);
    vq_kernel<<<NBLOCKS, THREADS, 0, stream>>>(z, cb, cbb, cnm, out);
}

// Round 6
// 562.885 us; speedup vs baseline: 1.1434x; 1.0160x over previous
//
#include <hip/hip_runtime.h>
#include <stdint.h>

// Problem constants (B=32, D=256, H=32, W=32, K=2048)
#define K_CODES 2048
#define DIM 256
#define NROWS 32768            // B*H*W
#define ROWS_PER_BLOCK 16
#define THREADS 512            // 8 waves
#define HW_STRIDE 1024         // H*W
#define QLOSS_OFFSET 8388608
#define PROB_OFFSET 8388609ULL
#define ZB_PITCH 264           // ushorts per LDS z-row: 256 + 8 pad
#define EP_PITCH 2052          // fp16 per prob row: 2048 + 4 pad (bank spread)
#define NBLOCKS (NROWS / ROWS_PER_BLOCK)   // 2048
#define CPX (NBLOCKS / 8)                  // 256 blocks per XCD chunk

typedef short v8s __attribute__((ext_vector_type(8)));   // 8 bf16 (MFMA operand)
typedef float v4f __attribute__((ext_vector_type(4)));
typedef __fp16 v4h __attribute__((ext_vector_type(4)));

__device__ __forceinline__ ushort f2bf(float x) {
    uint32_t u = __float_as_uint(x);
    return (ushort)((u + 0x7FFFu + ((u >> 16) & 1u)) >> 16);   // RNE
}

// Prep: codebook fp32 -> bf16 (ws), cnorm[k] = sum c^2, zero the q_loss slot.
__global__ void prep_kernel(const float* __restrict__ cb, ushort* __restrict__ cbb,
                            float* __restrict__ cnorm, float* __restrict__ qloss) {
    const int code = blockIdx.x;
    const int lane = threadIdx.x;     // 64 threads
    float4 v = ((const float4*)(cb + code * DIM))[lane];
    ushort4 o;
    o.x = f2bf(v.x); o.y = f2bf(v.y); o.z = f2bf(v.z); o.w = f2bf(v.w);
    ((ushort4*)(cbb + code * DIM))[lane] = o;
    float ss = v.x * v.x + v.y * v.y + v.z * v.z + v.w * v.w;
    #pragma unroll
    for (int m = 32; m >= 1; m >>= 1) ss += __shfl_xor(ss, m, 64);
    if (lane == 0) cnorm[code] = ss;
    if (code == 0 && lane == 0) *qloss = 0.f;
}

// 4 waves/EU -> 128-reg total budget; two 8-wave blocks co-reside per CU
// (LDS 75.8 KB/block is the binding 2-block limit).
__launch_bounds__(THREADS, 4)
__global__ void vq_kernel(const float* __restrict__ z, const float* __restrict__ cb,
                          const ushort* __restrict__ cbb, const float* __restrict__ cnorm,
                          float* __restrict__ out) {
    // eplds: fp16 exp matrix [16 rows][2052] = 64.1 KB. Its first 16 KB doubles
    // as the fp32 z staging area (zf) before the ct-loop starts writing exps.
    __shared__ __align__(16) ushort eplds[ROWS_PER_BLOCK * EP_PITCH];
    __shared__ ushort zb[ROWS_PER_BLOCK * ZB_PITCH];     // [m][k] bf16, padded
    __shared__ float red_sum[8][16];
    __shared__ float red_val[8][16];
    __shared__ int   red_code[8][16];
    __shared__ float row_sum[16];
    __shared__ int   row_idx[16];
    __shared__ float lred[8];

    const int t = threadIdx.x;
    // XCD-chunk swizzle (bijective: 2048 % 8 == 0): consecutive logical blocks
    // share 128B z/z_q lines -> keep them on one XCD's L2.
    const int bid = ((int)blockIdx.x & 7) * CPX + ((int)blockIdx.x >> 3);
    const int n0 = bid * ROWS_PER_BLOCK;                 // first global row
    const int bb = n0 >> 10;                             // batch index
    const int hw = n0 & 1023;                            // h*32 + w0 (16-aligned)
    const float* zbase = z + (size_t)bb * (DIM * HW_STRIDE) + hw;

    float* zf = (float*)eplds;                           // alias (pre-loop only)

    // ---- stage z -> zf [d][m]; keep own elements in zrf for the tail ----
    float zrf[8];
    #pragma unroll
    for (int j = 0; j < 2; ++j) {
        int i4 = t + j * THREADS;                        // 0..1023
        int d = i4 >> 2, m0 = (i4 & 3) << 2;
        float4 v = *(const float4*)(zbase + (size_t)d * HW_STRIDE + m0);
        zrf[4 * j + 0] = v.x; zrf[4 * j + 1] = v.y;
        zrf[4 * j + 2] = v.z; zrf[4 * j + 3] = v.w;
        *(float4*)&zf[d * 16 + m0] = v;
    }
    __syncthreads();
    // ---- transpose zf -> zb bf16 [m][k] for MFMA A-fragments ----
    #pragma unroll
    for (int j = 0; j < 4; ++j) {
        int i2 = t + j * THREADS;                        // 0..2047
        int m = i2 & 15, kp = i2 >> 4;                   // kp = k/2, 0..127
        float a0 = zf[(2 * kp) * 16 + m];
        float a1 = zf[(2 * kp + 1) * 16 + m];
        uint32_t pk = (uint32_t)f2bf(a0) | ((uint32_t)f2bf(a1) << 16);
        *(uint32_t*)&zb[m * ZB_PITCH + 2 * kp] = pk;
    }
    __syncthreads();
    // zf region dead from here; ct-loop writes exps into eplds.

    const int wave = t >> 6, lane = t & 63;
    const int q = lane >> 4, lm = lane & 15;
    const int c0 = wave * 256;                           // this wave's code range

    // A fragments: lane holds A[m=lm][k = ks*32 + q*8 + j], all 8 k-steps
    v8s afrag[8];
    const ushort* arow = &zb[lm * ZB_PITCH + q * 8];
    #pragma unroll
    for (int ks = 0; ks < 8; ++ks) afrag[ks] = *(const v8s*)(arow + ks * 32);

    // K-loop: 16 col-tiles x 8 k-steps, software-pipelined one tile deep.
    // sched_barrier(0) pins the ct+1 load issue BEFORE ct's MFMA chain so the
    // scheduler cannot sink the prefetch back to its uses.
    const ushort* bptr = cbb + (size_t)(c0 + lm) * DIM + q * 8;  // code = c0+ct*16+lm
    v8s bb0[8];
    #pragma unroll
    for (int ks = 0; ks < 8; ++ks) bb0[ks] = *(const v8s*)(bptr + ks * 32);
    float cn0 = cnorm[c0 + lm];

    __fp16* epf = (__fp16*)eplds;
    float sume[4] = {0.f, 0.f, 0.f, 0.f};
    float bval[4] = {-1e30f, -1e30f, -1e30f, -1e30f};
    int   bcode[4] = {0, 0, 0, 0};
    #pragma unroll
    for (int ct = 0; ct < 16; ++ct) {
        v8s bb1[8];
        float cn1;
        if (ct < 15) {
            const ushort* np = bptr + (size_t)(ct + 1) * (16 * DIM);
            #pragma unroll
            for (int ks = 0; ks < 8; ++ks) bb1[ks] = *(const v8s*)(np + ks * 32);
            cn1 = cnorm[c0 + (ct + 1) * 16 + lm];
        }
        __builtin_amdgcn_sched_barrier(0);               // loads stay issued above
        v4f a = {0.f, 0.f, 0.f, 0.f};
        #pragma unroll
        for (int ks = 0; ks < 8; ++ks)
            a = __builtin_amdgcn_mfma_f32_16x16x32_bf16(afrag[ks], bb0[ks], a, 0, 0, 0);
        const int code = c0 + ct * 16 + lm;
        #pragma unroll
        for (int r = 0; r < 4; ++r) {
            float l = 2.f * a[r] - cn0;                  // logit = 2 z.c - |c|^2 (|z|^2 cancels)
            float ev = __expf(l);
            sume[r] += ev;
            if (l > bval[r]) { bval[r] = l; bcode[r] = code; }
            // [row = q*4+r][col = code]; banks: 2 lanes/dword -> conflict-free
            epf[(q * 4 + r) * EP_PITCH + code] = (__fp16)ev;
        }
        cn0 = cn1;
        #pragma unroll
        for (int ks = 0; ks < 8; ++ks) bb0[ks] = bb1[ks];  // renamed away (full unroll)
    }
    // butterfly across the 16 lanes (lm) of each quad-row group
    #pragma unroll
    for (int m = 1; m <= 8; m <<= 1) {
        #pragma unroll
        for (int r = 0; r < 4; ++r) {
            sume[r] += __shfl_xor(sume[r], m, 64);
            float v2 = __shfl_xor(bval[r], m, 64);
            int   c2 = __shfl_xor(bcode[r], m, 64);
            if (v2 > bval[r] || (v2 == bval[r] && c2 < bcode[r])) { bval[r] = v2; bcode[r] = c2; }
        }
    }
    if (lm == 0) {
        #pragma unroll
        for (int r = 0; r < 4; ++r) {
            red_sum[wave][q * 4 + r]  = sume[r];
            red_val[wave][q * 4 + r]  = bval[r];
            red_code[wave][q * 4 + r] = bcode[r];
        }
    }
    __syncthreads();
    if (t < 16) {
        float s = 0.f, bv = -1e30f;
        int bc = 0;
        #pragma unroll
        for (int w = 0; w < 8; ++w) {
            s += red_sum[w][t];
            float v = red_val[w][t];
            int   c = red_code[w][t];
            if (v > bv || (v == bv && c < bc)) { bv = v; bc = c; }
        }
        row_sum[t] = s;
        row_idx[t] = bc;
    }
    __syncthreads();

    // ---- z_q gather: issue codebook loads early (L2-hot, <=16 distinct rows);
    //      they complete while the prob store stream below is in flight ----
    float cv[8];
    #pragma unroll
    for (int j = 0; j < 2; ++j) {
        int i4 = t + j * THREADS;
        int d = i4 >> 2, m0 = (i4 & 3) << 2;
        #pragma unroll
        for (int i = 0; i < 4; ++i) cv[4 * j + i] = cb[row_idx[m0 + i] * DIM + d];
    }

    // ---- distance_prob: LDS-transposed coalesced stream, NONTEMPORAL.
    //      Each wave instruction covers 8 full 128B lines (no RMW possible),
    //      and nt keeps this 268 MB stream from evicting cbb out of L2. ----
    float* prob = out + PROB_OFFSET;
    #pragma unroll
    for (int rr = 0; rr < ROWS_PER_BLOCK; ++rr) {
        float rs = 1.f / row_sum[rr];                    // wave-uniform broadcast
        v4h e = *(const v4h*)&epf[rr * EP_PITCH + t * 4];
        v4f o = { e[0] * rs, e[1] * rs, e[2] * rs, e[3] * rs };
        __builtin_nontemporal_store(o, (v4f*)(prob + (size_t)(n0 + rr) * K_CODES + t * 4));
    }

    // ---- z_q store (normal stores: 64B chunks need L2 merging) + q_loss ----
    float lacc = 0.f;
    #pragma unroll
    for (int j = 0; j < 2; ++j) {
        int i4 = t + j * THREADS;
        int d = i4 >> 2, m0 = (i4 & 3) << 2;
        float ov[4];
        #pragma unroll
        for (int i = 0; i < 4; ++i) {
            float cvv = cv[4 * j + i];
            float df = zrf[4 * j + i] - cvv;
            lacc += df * df;
            ov[i] = cvv;
        }
        v4f o4 = {ov[0], ov[1], ov[2], ov[3]};
        *(v4f*)(out + (size_t)bb * (DIM * HW_STRIDE) + hw + (size_t)d * HW_STRIDE + m0) = o4;
    }
    #pragma unroll
    for (int m = 32; m >= 1; m >>= 1) lacc += __shfl_xor(lacc, m, 64);
    if (lane == 0) lred[wave] = lacc;
    __syncthreads();
    if (t == 0) {
        float s = 0.f;
        #pragma unroll
        for (int w = 0; w < 8; ++w) s += lred[w];
        // q_loss = (1 + BETA) * mean((z_q - z)^2); both loss terms coincide in fwd
        atomicAdd(out + QLOSS_OFFSET, s * (1.25f / 8388608.f));
    }
}

extern "C" void kernel_launch(void* const* d_in, const int* in_sizes, int n_in,
                              void* d_out, int out_size, void* d_ws, size_t ws_size,
                              hipStream_t stream) {
    const float* z  = (const float*)d_in[0];   // (32,256,32,32) fp32
    const float* cb = (const float*)d_in[1];   // (2048,256) fp32
    float* out = (float*)d_out;
    ushort* cbb  = (ushort*)d_ws;                                  // bf16 codebook, 1 MB
    float*  cnm  = (float*)((char*)d_ws + (size_t)K_CODES * DIM * sizeof(ushort));
    prep_kernel<<<K_CODES, 64, 0, stream>>>(cb, cbb, cnm, out + QLOSS_OFFSET);
    vq_kernel<<<NBLOCKS, THREADS, 0, stream>>>(z, cb, cbb, cnm, out);
}